// Round 8
// baseline (285.627 us; speedup 1.0000x reference)
//
#include <hip/hip_runtime.h>

typedef unsigned short USHORT;
typedef __attribute__((ext_vector_type(8))) short short8;
typedef __attribute__((ext_vector_type(4))) float f32x4;

#define NB   16
#define NC   512
#define NHW  4096
#define NT   77
#define NF   768
#define NHEAD 8
#define NDH  64
#define TPAD 80
#define TPAD2 96
#define BKS  64

__device__ __forceinline__ USHORT f2bf(float f){
  unsigned u = __builtin_bit_cast(unsigned, f);
  u += 0x7fffu + ((u >> 16) & 1u);
  return (USHORT)(u >> 16);
}
__device__ __forceinline__ unsigned pack2(float a, float b){
  return (unsigned)f2bf(a) | ((unsigned)f2bf(b) << 16);
}

__device__ __forceinline__ void gload16(const void* g, void* l){
  __builtin_amdgcn_global_load_lds((const __attribute__((address_space(1))) unsigned*)g,
                                   (__attribute__((address_space(3))) unsigned*)l, 16, 0, 0);
}

// XCD-aware swizzle of a 32-wide tile index (T1).
__device__ __forceinline__ int xcd_swz32(int x){ return ((x & 7) << 2) | (x >> 3); }

// ---------------- single-launch f32 -> bf16 convert of all 5 arrays ----------------
__global__ __launch_bounds__(256) void cvt_all_kernel(const float* __restrict__ s0, USHORT* __restrict__ d0, int n0,
                                                      const float* __restrict__ s1, USHORT* __restrict__ d1, int n1,
                                                      const float* __restrict__ s2, USHORT* __restrict__ d2, int n2,
                                                      const float* __restrict__ s3, USHORT* __restrict__ d3, int n3,
                                                      const float* __restrict__ s4, USHORT* __restrict__ d4, int n4){
  int i = blockIdx.x * 256 + threadIdx.x;
  const float* s; USHORT* d;
  if (i < n0){ s = s0; d = d0; }
  else { i -= n0;
    if (i < n1){ s = s1; d = d1; }
    else { i -= n1;
      if (i < n2){ s = s2; d = d2; }
      else { i -= n2;
        if (i < n3){ s = s3; d = d3; }
        else { i -= n3;
          if (i >= n4) return;
          s = s4; d = d4; } } } }
  float4 v = ((const float4*)s)[i];
  uint2 pk; pk.x = pack2(v.x, v.y); pk.y = pack2(v.z, v.w);
  ((uint2*)d)[i] = pk;
}

// ---------------- GroupNorm stats: one block per (b,group) ----------------
__global__ __launch_bounds__(256) void gnstats_kernel(const float* __restrict__ x, float2* __restrict__ stats){
  int gid = blockIdx.x;                       // 0..511, group data contiguous: 65536 floats
  const float4* p = (const float4*)(x + (size_t)gid * 65536);
  float s = 0.f, s2 = 0.f;
  for (int i = threadIdx.x; i < 16384; i += 256){
    float4 v = p[i];
    s  += v.x + v.y + v.z + v.w;
    s2 += v.x*v.x + v.y*v.y + v.z*v.z + v.w*v.w;
  }
  #pragma unroll
  for (int off = 32; off; off >>= 1){ s += __shfl_down(s, off); s2 += __shfl_down(s2, off); }
  __shared__ float red[8];
  int wv = threadIdx.x >> 6;
  if ((threadIdx.x & 63) == 0){ red[wv] = s; red[4 + wv] = s2; }
  __syncthreads();
  if (threadIdx.x == 0){
    float S  = red[0] + red[1] + red[2] + red[3];
    float S2 = red[4] + red[5] + red[6] + red[7];
    float mu = S * (1.0f / 65536.0f);
    float var = S2 * (1.0f / 65536.0f) - mu * mu;
    stats[gid] = make_float2(mu, 1.0f / sqrtf(var + 1e-5f));
  }
}

// ---------------- normalize + transpose -> xn_T[b][s][c] bf16 ----------------
__global__ __launch_bounds__(256) void gnorm_tr_kernel(const float* __restrict__ x, const float2* __restrict__ stats,
                                                       const float* __restrict__ gamma, const float* __restrict__ beta,
                                                       USHORT* __restrict__ xnT){
  __shared__ float tile[64][65];
  int b = blockIdx.z, c0 = blockIdx.y * 64, s0 = blockIdx.x * 64;
  int col = threadIdx.x & 63;
  int row4 = threadIdx.x >> 6;
  const float* xp = x + ((size_t)b * NC + c0) * NHW + s0;
  #pragma unroll
  for (int i = 0; i < 16; i++){
    int r = i * 4 + row4;
    tile[r][col] = xp[(size_t)r * NHW + col];
  }
  __syncthreads();
  int c = c0 + col;
  int g = c >> 4;
  float2 st = stats[b * 32 + g];
  float ga = gamma[c], be = beta[c];
  USHORT* op = xnT + ((size_t)b * NHW + s0) * NC + c;
  #pragma unroll
  for (int i = 0; i < 16; i++){
    int s = i * 4 + row4;
    float v = (tile[col][s] - st.x) * st.y * ga + be;
    op[(size_t)s * NC] = f2bf(v);
  }
}

// ---------------- 128x128-tile single-buffer LDS GEMM core (R2: best measured) ----------------
// LDS rows 128B (BK=64 bf16); slot = 16B unit; swizzle slot ^= (row&7) on BOTH the global
// staging source and the ds_read address. Single buffer; TLP hides latency.
// NOTE: acc[4][4] = 64 regs; R5 showed bound>=5 (cap 102->48 alloc) spills the accumulator.
// Bound 4 keeps cap at 128 which fits the ~100-reg live set.
__device__ __forceinline__ void gemm128_core(const USHORT* __restrict__ A, const USHORT* __restrict__ B,
                                             int m0, size_t brow0, USHORT* Alds, USHORT* Blds,
                                             f32x4 (&acc)[4][4]){
  const int tid = threadIdx.x;
  const int lane = tid & 63, wave = tid >> 6;
  const int l15 = lane & 15, lg = lane >> 4;
  const int wm = wave >> 1, wn = wave & 1;
  const int srow = lane >> 3, sslot = lane & 7;

  #pragma unroll
  for (int i = 0; i < 4; i++)
    #pragma unroll
    for (int j = 0; j < 4; j++) acc[i][j] = f32x4{0.f, 0.f, 0.f, 0.f};

  for (int k0 = 0; k0 < 512; k0 += BKS){
    #pragma unroll
    for (int i = 0; i < 4; i++){
      const int r0 = wave * 32 + i * 8;
      const int row = r0 + srow;
      const int slot = sslot ^ (row & 7);
      gload16(A + (size_t)(m0 + row) * NC + k0 + slot * 8, Alds + r0 * BKS);
      gload16(B + brow0 + (size_t)row * NC + k0 + slot * 8, Blds + r0 * BKS);
    }
    __syncthreads();
    #pragma unroll
    for (int ks = 0; ks < 2; ks++){
      short8 af[4], bf[4];
      #pragma unroll
      for (int i = 0; i < 4; i++){
        const int row = wm * 64 + i * 16 + l15;
        af[i] = *(const short8*)(Alds + row * BKS + (((ks * 4 + lg) ^ (row & 7)) * 8));
      }
      #pragma unroll
      for (int j = 0; j < 4; j++){
        const int row = wn * 64 + j * 16 + l15;
        bf[j] = *(const short8*)(Blds + row * BKS + (((ks * 4 + lg) ^ (row & 7)) * 8));
      }
      #pragma unroll
      for (int i = 0; i < 4; i++)
        #pragma unroll
        for (int j = 0; j < 4; j++)
          acc[i][j] = __builtin_amdgcn_mfma_f32_16x16x32_bf16(af[i], bf[j], acc[i][j], 0, 0, 0);
    }
    __syncthreads();
  }
}

// ---------------- FUSED Q-GEMM + attention ----------------
__global__ __launch_bounds__(256, 3) void qattn_kernel(const USHORT* __restrict__ Aw, const USHORT* __restrict__ Bx,
                                                       const float* __restrict__ bias,
                                                       const USHORT* __restrict__ kb, const USHORT* __restrict__ vb,
                                                       USHORT* __restrict__ attnT){
  __shared__ USHORT smem[24576];   // 48 KB
  const int lane = threadIdx.x & 63, wave = threadIdx.x >> 6;
  const int l15 = lane & 15, lg = lane >> 4;
  const int b = blockIdx.z;
  const int xx = xcd_swz32(blockIdx.x);
  const int m0b = blockIdx.y * 128;
  const size_t brow0 = ((size_t)b * NHW + xx * 128) * NC;
  f32x4 acc[4][4];
  gemm128_core(Aw, Bx, m0b, brow0, smem, smem + 8192, acc);

  const int wm = wave >> 1, wn = wave & 1;
  const int h = blockIdx.y * 2 + wm;
  const int m0 = h * 64;                      // head channel base
  const int s0 = xx * 128 + wn * 64;          // this wave's 64 query rows
  const size_t bh = (size_t)b * NHEAD + h;
  char* qt = (char*)(smem + wave * 6144);     // 12 KB wave-private region

  // transpose Q (+bias) into qt[s][d] bf16, XOR-swizzled
  #pragma unroll
  for (int i = 0; i < 4; i++){
    const int dbase = i * 16 + lg * 4;
    float b0 = bias[m0 + dbase], b1 = bias[m0 + dbase + 1];
    float b2 = bias[m0 + dbase + 2], b3 = bias[m0 + dbase + 3];
    #pragma unroll
    for (int j = 0; j < 4; j++){
      const int s = j * 16 + l15;
      uint2 pk;
      pk.x = pack2(acc[i][j][0] + b0, acc[i][j][1] + b1);
      pk.y = pack2(acc[i][j][2] + b2, acc[i][j][3] + b3);
      *(uint2*)(qt + s * 128 + ((dbase * 2) ^ ((s & 7) << 4))) = pk;
    }
  }
  // read Q A-fragments (row = s = i*16+l15, k = d contiguous)
  short8 aq[4][2];
  #pragma unroll
  for (int i = 0; i < 4; i++){
    const int s = i * 16 + l15;
    #pragma unroll
    for (int ks = 0; ks < 2; ks++)
      aq[i][ks] = *(const short8*)(qt + s * 128 + ((ks * 64 + lg * 16) ^ ((s & 7) << 4)));
  }

  // P tile reuses the same 12 KB region: [64][96] bf16. Zero pad cols 80..95 (row = lane).
  USHORT* plds = (USHORT*)qt;
  uint4 z{0u, 0u, 0u, 0u};
  *(uint4*)(qt + lane * 192 + 160) = z;
  *(uint4*)(qt + lane * 192 + 176) = z;

  // K B-fragments (col = token = l15, k = d contiguous)
  short8 bk[5][2];
  const USHORT* kp = kb + bh * TPAD * NDH;
  #pragma unroll
  for (int j = 0; j < 5; j++)
    #pragma unroll
    for (int ks = 0; ks < 2; ks++)
      bk[j][ks] = *(const short8*)(kp + (j * 16 + l15) * NDH + ks * 32 + lg * 8);

  f32x4 sacc[4][5];
  #pragma unroll
  for (int i = 0; i < 4; i++)
    #pragma unroll
    for (int j = 0; j < 5; j++) sacc[i][j] = f32x4{0.f, 0.f, 0.f, 0.f};
  #pragma unroll
  for (int ks = 0; ks < 2; ks++)
    #pragma unroll
    for (int i = 0; i < 4; i++)
      #pragma unroll
      for (int j = 0; j < 5; j++)
        sacc[i][j] = __builtin_amdgcn_mfma_f32_16x16x32_bf16(aq[i][ks], bk[j][ks], sacc[i][j], 0, 0, 0);

  // softmax per row-tile i; rows = lg*4+r live across the 16 lanes sharing lg
  const float scale = 0.125f;
  #pragma unroll
  for (int i = 0; i < 4; i++){
    float v[5][4], mx[4], sm[4];
    #pragma unroll
    for (int r = 0; r < 4; r++) mx[r] = -3.0e38f;
    #pragma unroll
    for (int j = 0; j < 5; j++)
      #pragma unroll
      for (int r = 0; r < 4; r++){
        float t = sacc[i][j][r] * scale;
        if (j == 4 && l15 >= 13) t = -3.0e38f;   // tokens 77..79 masked
        v[j][r] = t;
        mx[r] = fmaxf(mx[r], t);
      }
    #pragma unroll
    for (int r = 0; r < 4; r++)
      #pragma unroll
      for (int d = 1; d < 16; d <<= 1) mx[r] = fmaxf(mx[r], __shfl_xor(mx[r], d));
    #pragma unroll
    for (int r = 0; r < 4; r++) sm[r] = 0.f;
    #pragma unroll
    for (int j = 0; j < 5; j++)
      #pragma unroll
      for (int r = 0; r < 4; r++){
        float p = __expf(v[j][r] - mx[r]);
        v[j][r] = p;
        sm[r] += p;
      }
    #pragma unroll
    for (int r = 0; r < 4; r++)
      #pragma unroll
      for (int d = 1; d < 16; d <<= 1) sm[r] += __shfl_xor(sm[r], d);
    #pragma unroll
    for (int r = 0; r < 4; r++){
      float inv = 1.0f / sm[r];
      #pragma unroll
      for (int j = 0; j < 5; j++)
        plds[(i * 16 + lg * 4 + r) * TPAD2 + j * 16 + l15] = f2bf(v[j][r] * inv);
    }
  }

  // PV: O^T = V^T (A, from global vb[d][96]) x P^T (B, from LDS plds[s][96])
  f32x4 oacc[4][4];
  #pragma unroll
  for (int it = 0; it < 4; it++)
    #pragma unroll
    for (int jt = 0; jt < 4; jt++) oacc[it][jt] = f32x4{0.f, 0.f, 0.f, 0.f};
  const USHORT* vp = vb + bh * NDH * TPAD2;
  #pragma unroll
  for (int ks = 0; ks < 3; ks++){
    short8 av[4], bpv[4];
    #pragma unroll
    for (int it = 0; it < 4; it++)
      av[it] = *(const short8*)(vp + (it * 16 + l15) * TPAD2 + ks * 32 + lg * 8);
    #pragma unroll
    for (int jt = 0; jt < 4; jt++)
      bpv[jt] = *(const short8*)(plds + (jt * 16 + l15) * TPAD2 + ks * 32 + lg * 8);
    #pragma unroll
    for (int it = 0; it < 4; it++)
      #pragma unroll
      for (int jt = 0; jt < 4; jt++)
        oacc[it][jt] = __builtin_amdgcn_mfma_f32_16x16x32_bf16(av[it], bpv[jt], oacc[it][jt], 0, 0, 0);
  }

  // epilogue: D row = channel (it*16+lg*4+reg), col = s-local (jt*16+l15); pack 4 channels -> 8B
  // non-temporal: attnT not re-read until projgemm (won't survive in L2 anyway); keep L2 for xnT
  USHORT* ob = attnT + ((size_t)b * NHW + s0) * NC + h * NDH;
  #pragma unroll
  for (int it = 0; it < 4; it++)
    #pragma unroll
    for (int jt = 0; jt < 4; jt++){
      const int sl = jt * 16 + l15;
      uint2 pk;
      pk.x = pack2(oacc[it][jt][0], oacc[it][jt][1]);
      pk.y = pack2(oacc[it][jt][2], oacc[it][jt][3]);
      unsigned long long w = (unsigned long long)pk.x | ((unsigned long long)pk.y << 32);
      __builtin_nontemporal_store(w, (unsigned long long*)(ob + (size_t)sl * NC + it * 16 + lg * 4));
    }
}

// ---------------- proj GEMM + bias + residual -> out fp32 [b][c][hw] ----------------
// bound (256,4): VGPR cap 128 >= ~100 live -> no spill (R5's bound-5 cap was too tight);
// lets 4 blocks/CU be resident if the allocator was the limiter.
__global__ __launch_bounds__(256, 4) void projgemm_kernel(const USHORT* __restrict__ Aw, const USHORT* __restrict__ Battn,
                                                          const float* __restrict__ bias, const float* __restrict__ xres,
                                                          float* __restrict__ out){
  __shared__ USHORT Alds[128 * BKS], Blds[128 * BKS];
  const int b = blockIdx.z;
  const int xx = xcd_swz32(blockIdx.x);
  const int m0b = blockIdx.y * 128;
  const size_t brow0 = ((size_t)b * NHW + xx * 128) * NC;
  f32x4 acc[4][4];
  gemm128_core(Aw, Battn, m0b, brow0, Alds, Blds, acc);

  const int lane = threadIdx.x & 63, wave = threadIdx.x >> 6;
  const int l15 = lane & 15, lg = lane >> 4;
  const int m0 = m0b + (wave >> 1) * 64;
  const int n0 = xx * 128 + (wave & 1) * 64;
  #pragma unroll
  for (int i = 0; i < 4; i++){
    const int ob = m0 + i * 16 + lg * 4;
    #pragma unroll
    for (int r = 0; r < 4; r++){
      const int oc = ob + r;
      const float bb = bias[oc];
      #pragma unroll
      for (int j = 0; j < 4; j++){
        const int s = n0 + j * 16 + l15;
        const size_t idx = ((size_t)b * NC + oc) * NHW + s;
        float xr = __builtin_nontemporal_load(&xres[idx]);
        __builtin_nontemporal_store(acc[i][j][r] + bb + xr, &out[idx]);
      }
    }
  }
}

// ---------------- small-K MFMA core for the 77-token projections ----------------
template<int KLEN>
__device__ __forceinline__ void mfma_core(const USHORT* const (&ap)[4], const USHORT* const (&bp)[4],
                                          f32x4 (&acc)[4][4]){
  short8 a_c[4], b_c[4];
  #pragma unroll
  for (int i = 0; i < 4; i++){ a_c[i] = *(const short8*)ap[i]; b_c[i] = *(const short8*)bp[i]; }
  #pragma unroll 2
  for (int k0 = 0; k0 < KLEN; k0 += 32){
    short8 a_n[4], b_n[4];
    if (k0 + 32 < KLEN){
      #pragma unroll
      for (int i = 0; i < 4; i++){
        a_n[i] = *(const short8*)(ap[i] + k0 + 32);
        b_n[i] = *(const short8*)(bp[i] + k0 + 32);
      }
    }
    #pragma unroll
    for (int i = 0; i < 4; i++)
      #pragma unroll
      for (int j = 0; j < 4; j++)
        acc[i][j] = __builtin_amdgcn_mfma_f32_16x16x32_bf16(a_c[i], b_c[j], acc[i][j], 0, 0, 0);
    #pragma unroll
    for (int i = 0; i < 4; i++){ a_c[i] = a_n[i]; b_c[i] = b_n[i]; }
  }
}

// ---------------- K+V GEMM (single launch, mode = blockIdx.y) + raw-reshape scatter ----------------
__global__ __launch_bounds__(256, 2) void kvgemm_kernel(const USHORT* __restrict__ kw, const USHORT* __restrict__ vw,
                                                        const USHORT* __restrict__ Tx,
                                                        const float* __restrict__ kbias, const float* __restrict__ vbias,
                                                        USHORT* __restrict__ kdst, USHORT* __restrict__ vdst){
  const int lane = threadIdx.x & 63, wave = threadIdx.x >> 6;
  const int l15 = lane & 15, lg = lane >> 4;
  const int b = blockIdx.z;
  const int mode = blockIdx.y;
  const USHORT* Wt = mode ? vw : kw;
  const float* bias = mode ? vbias : kbias;
  USHORT* dst = mode ? vdst : kdst;
  const int m0 = (wave >> 1) * 64;                    // token tile base
  const int n0 = blockIdx.x * 128 + (wave & 1) * 64;  // channel base
  const USHORT* ap[4]; const USHORT* bp[4];
  #pragma unroll
  for (int i = 0; i < 4; i++){
    int r = m0 + i * 16 + l15; r = r > 76 ? 76 : r;
    ap[i] = Tx + ((size_t)b * NT + r) * NF + lg * 8;
  }
  #pragma unroll
  for (int i = 0; i < 4; i++) bp[i] = Wt + (size_t)(n0 + i * 16 + l15) * NF + lg * 8;
  f32x4 acc[4][4];
  #pragma unroll
  for (int i = 0; i < 4; i++)
    #pragma unroll
    for (int j = 0; j < 4; j++) acc[i][j] = f32x4{0.f, 0.f, 0.f, 0.f};
  mfma_core<NF>(ap, bp, acc);
  #pragma unroll
  for (int i = 0; i < 4; i++){
    const int tb = m0 + i * 16 + lg * 4;
    #pragma unroll
    for (int r = 0; r < 4; r++){
      const int t = tb + r;
      if (t < NT){
        #pragma unroll
        for (int j = 0; j < 4; j++){
          const int c = n0 + j * 16 + l15;
          float v = acc[i][j][r] + bias[c];
          // raw reshape (b,77,512)->(b,8,64,77): flat i = t*512+c -> h=i/4928, d=(i%4928)/77, tt=i%77
          int fi = t * NC + c;
          int hh = fi / 4928;
          int rem = fi - hh * 4928;
          int dd = rem / 77;
          int tt = rem - dd * 77;
          size_t bhh = (size_t)(b * NHEAD + hh);
          if (mode == 0) dst[(bhh * TPAD + tt) * NDH + dd] = f2bf(v);
          else           dst[(bhh * NDH + dd) * TPAD2 + tt] = f2bf(v);
        }
      }
    }
  }
}

extern "C" void kernel_launch(void* const* d_in, const int* in_sizes, int n_in,
                              void* d_out, int out_size, void* d_ws, size_t ws_size,
                              hipStream_t stream){
  const float* x    = (const float*)d_in[0];
  const float* text = (const float*)d_in[1];
  const float* gn_g = (const float*)d_in[2];
  const float* gn_b = (const float*)d_in[3];
  const float* q_w  = (const float*)d_in[4];
  const float* q_b  = (const float*)d_in[5];
  const float* k_w  = (const float*)d_in[6];
  const float* k_b  = (const float*)d_in[7];
  const float* v_w  = (const float*)d_in[8];
  const float* v_b  = (const float*)d_in[9];
  const float* p_w  = (const float*)d_in[10];
  const float* p_b  = (const float*)d_in[11];
  float* out = (float*)d_out;

  char* ws = (char*)d_ws;
  size_t off = 0;
  auto alloc = [&](size_t bytes){ size_t o = off; off = (off + bytes + 255) & ~(size_t)255; return o; };
  size_t o_stats = alloc(512 * 8);
  size_t o_qwb   = alloc((size_t)NC * NC * 2);
  size_t o_pwb   = alloc((size_t)NC * NC * 2);
  size_t o_kwb   = alloc((size_t)NC * NF * 2);
  size_t o_vwb   = alloc((size_t)NC * NF * 2);
  size_t o_txb   = alloc((size_t)NB * NT * NF * 2);
  size_t o_kb    = alloc((size_t)NB * NHEAD * TPAD * NDH * 2);
  size_t o_vb    = alloc((size_t)NB * NHEAD * NDH * TPAD2 * 2);
  size_t o_xnT   = alloc((size_t)NB * NHW * NC * 2);
  size_t o_attnT = alloc((size_t)NB * NHW * NC * 2);
  (void)ws_size; (void)in_sizes; (void)n_in; (void)out_size;

  float2* stats = (float2*)(ws + o_stats);
  USHORT* qwb = (USHORT*)(ws + o_qwb);
  USHORT* pwb = (USHORT*)(ws + o_pwb);
  USHORT* kwb = (USHORT*)(ws + o_kwb);
  USHORT* vwb = (USHORT*)(ws + o_vwb);
  USHORT* txb = (USHORT*)(ws + o_txb);
  USHORT* kbuf = (USHORT*)(ws + o_kb);
  USHORT* vbuf = (USHORT*)(ws + o_vb);
  USHORT* xnT = (USHORT*)(ws + o_xnT);
  USHORT* attnT = (USHORT*)(ws + o_attnT);

  // single convert launch: q_w, p_w, k_w, v_w, text (sizes in float4 units)
  const int n0 = (NC * NC) / 4, n1 = (NC * NC) / 4, n2 = (NC * NF) / 4, n3 = (NC * NF) / 4,
            n4 = (NB * NT * NF) / 4;
  const int ntot = n0 + n1 + n2 + n3 + n4;
  hipLaunchKernelGGL(cvt_all_kernel, dim3((ntot + 255) / 256), dim3(256), 0, stream,
                     q_w, qwb, n0, p_w, pwb, n1, k_w, kwb, n2, v_w, vwb, n3, text, txb, n4);

  hipLaunchKernelGGL(gnstats_kernel, dim3(512), dim3(256), 0, stream, x, stats);
  hipLaunchKernelGGL(gnorm_tr_kernel, dim3(64, 8, 16), dim3(256), 0, stream, x, stats, gn_g, gn_b, xnT);
  hipLaunchKernelGGL(kvgemm_kernel, dim3(4, 2, 16), dim3(256), 0, stream, kwb, vwb, txb, k_b, v_b, kbuf, vbuf);
  hipLaunchKernelGGL(qattn_kernel, dim3(32, 4, 16), dim3(256), 0, stream, qwb, xnT, q_b, kbuf, vbuf, attnT);
  hipLaunchKernelGGL(projgemm_kernel, dim3(32, 4, 16), dim3(256), 0, stream, pwb, attnT, p_b, x, out);
}

// Round 9
// 259.825 us; speedup vs baseline: 1.0993x; 1.0993x over previous
//
#include <hip/hip_runtime.h>

typedef unsigned short USHORT;
typedef __attribute__((ext_vector_type(8))) short short8;
typedef __attribute__((ext_vector_type(4))) float f32x4;

#define NB   16
#define NC   512
#define NHW  4096
#define NT   77
#define NF   768
#define NHEAD 8
#define NDH  64
#define TPAD 80
#define TPAD2 96
#define PSTR 104   // P-tile LDS row stride in shorts: 208B = 52 dwords == 20 mod 32 banks (96 was 16 mod 32 -> 8-way conflicts)
#define BKS  64

__device__ __forceinline__ USHORT f2bf(float f){
  unsigned u = __builtin_bit_cast(unsigned, f);
  u += 0x7fffu + ((u >> 16) & 1u);
  return (USHORT)(u >> 16);
}
__device__ __forceinline__ unsigned pack2(float a, float b){
  return (unsigned)f2bf(a) | ((unsigned)f2bf(b) << 16);
}

__device__ __forceinline__ void gload16(const void* g, void* l){
  __builtin_amdgcn_global_load_lds((const __attribute__((address_space(1))) unsigned*)g,
                                   (__attribute__((address_space(3))) unsigned*)l, 16, 0, 0);
}

// XCD-aware swizzle of a 32-wide tile index (T1).
__device__ __forceinline__ int xcd_swz32(int x){ return ((x & 7) << 2) | (x >> 3); }

// ---------------- single-launch f32 -> bf16 convert of all 5 arrays ----------------
__global__ __launch_bounds__(256) void cvt_all_kernel(const float* __restrict__ s0, USHORT* __restrict__ d0, int n0,
                                                      const float* __restrict__ s1, USHORT* __restrict__ d1, int n1,
                                                      const float* __restrict__ s2, USHORT* __restrict__ d2, int n2,
                                                      const float* __restrict__ s3, USHORT* __restrict__ d3, int n3,
                                                      const float* __restrict__ s4, USHORT* __restrict__ d4, int n4){
  int i = blockIdx.x * 256 + threadIdx.x;
  const float* s; USHORT* d;
  if (i < n0){ s = s0; d = d0; }
  else { i -= n0;
    if (i < n1){ s = s1; d = d1; }
    else { i -= n1;
      if (i < n2){ s = s2; d = d2; }
      else { i -= n2;
        if (i < n3){ s = s3; d = d3; }
        else { i -= n3;
          if (i >= n4) return;
          s = s4; d = d4; } } } }
  float4 v = ((const float4*)s)[i];
  uint2 pk; pk.x = pack2(v.x, v.y); pk.y = pack2(v.z, v.w);
  ((uint2*)d)[i] = pk;
}

// ---------------- GroupNorm stats: one block per (b,group) ----------------
__global__ __launch_bounds__(256) void gnstats_kernel(const float* __restrict__ x, float2* __restrict__ stats){
  int gid = blockIdx.x;                       // 0..511, group data contiguous: 65536 floats
  const float4* p = (const float4*)(x + (size_t)gid * 65536);
  float s = 0.f, s2 = 0.f;
  for (int i = threadIdx.x; i < 16384; i += 256){
    float4 v = p[i];
    s  += v.x + v.y + v.z + v.w;
    s2 += v.x*v.x + v.y*v.y + v.z*v.z + v.w*v.w;
  }
  #pragma unroll
  for (int off = 32; off; off >>= 1){ s += __shfl_down(s, off); s2 += __shfl_down(s2, off); }
  __shared__ float red[8];
  int wv = threadIdx.x >> 6;
  if ((threadIdx.x & 63) == 0){ red[wv] = s; red[4 + wv] = s2; }
  __syncthreads();
  if (threadIdx.x == 0){
    float S  = red[0] + red[1] + red[2] + red[3];
    float S2 = red[4] + red[5] + red[6] + red[7];
    float mu = S * (1.0f / 65536.0f);
    float var = S2 * (1.0f / 65536.0f) - mu * mu;
    stats[gid] = make_float2(mu, 1.0f / sqrtf(var + 1e-5f));
  }
}

// ---------------- normalize + transpose -> xn_T[b][s][c] bf16 ----------------
__global__ __launch_bounds__(256) void gnorm_tr_kernel(const float* __restrict__ x, const float2* __restrict__ stats,
                                                       const float* __restrict__ gamma, const float* __restrict__ beta,
                                                       USHORT* __restrict__ xnT){
  __shared__ float tile[64][65];
  int b = blockIdx.z, c0 = blockIdx.y * 64, s0 = blockIdx.x * 64;
  int col = threadIdx.x & 63;
  int row4 = threadIdx.x >> 6;
  const float* xp = x + ((size_t)b * NC + c0) * NHW + s0;
  #pragma unroll
  for (int i = 0; i < 16; i++){
    int r = i * 4 + row4;
    tile[r][col] = xp[(size_t)r * NHW + col];
  }
  __syncthreads();
  int c = c0 + col;
  int g = c >> 4;
  float2 st = stats[b * 32 + g];
  float ga = gamma[c], be = beta[c];
  USHORT* op = xnT + ((size_t)b * NHW + s0) * NC + c;
  #pragma unroll
  for (int i = 0; i < 16; i++){
    int s = i * 4 + row4;
    float v = (tile[col][s] - st.x) * st.y * ga + be;
    op[(size_t)s * NC] = f2bf(v);
  }
}

// ---------------- 128x128-tile single-buffer LDS GEMM core (R2/R6: best measured) ----------------
// LDS rows 128B (BK=64 bf16); slot = 16B unit; swizzle slot ^= (row&7) on BOTH the global
// staging source and the ds_read address. Single buffer; TLP hides latency.
// DO NOT raise min-waves: bound>=4 regressed twice (R5 spill, R7 sched) - keep 3.
__device__ __forceinline__ void gemm128_core(const USHORT* __restrict__ A, const USHORT* __restrict__ B,
                                             int m0, size_t brow0, USHORT* Alds, USHORT* Blds,
                                             f32x4 (&acc)[4][4]){
  const int tid = threadIdx.x;
  const int lane = tid & 63, wave = tid >> 6;
  const int l15 = lane & 15, lg = lane >> 4;
  const int wm = wave >> 1, wn = wave & 1;
  const int srow = lane >> 3, sslot = lane & 7;

  #pragma unroll
  for (int i = 0; i < 4; i++)
    #pragma unroll
    for (int j = 0; j < 4; j++) acc[i][j] = f32x4{0.f, 0.f, 0.f, 0.f};

  for (int k0 = 0; k0 < 512; k0 += BKS){
    #pragma unroll
    for (int i = 0; i < 4; i++){
      const int r0 = wave * 32 + i * 8;
      const int row = r0 + srow;
      const int slot = sslot ^ (row & 7);
      gload16(A + (size_t)(m0 + row) * NC + k0 + slot * 8, Alds + r0 * BKS);
      gload16(B + brow0 + (size_t)row * NC + k0 + slot * 8, Blds + r0 * BKS);
    }
    __syncthreads();
    #pragma unroll
    for (int ks = 0; ks < 2; ks++){
      short8 af[4], bf[4];
      #pragma unroll
      for (int i = 0; i < 4; i++){
        const int row = wm * 64 + i * 16 + l15;
        af[i] = *(const short8*)(Alds + row * BKS + (((ks * 4 + lg) ^ (row & 7)) * 8));
      }
      #pragma unroll
      for (int j = 0; j < 4; j++){
        const int row = wn * 64 + j * 16 + l15;
        bf[j] = *(const short8*)(Blds + row * BKS + (((ks * 4 + lg) ^ (row & 7)) * 8));
      }
      #pragma unroll
      for (int i = 0; i < 4; i++)
        #pragma unroll
        for (int j = 0; j < 4; j++)
          acc[i][j] = __builtin_amdgcn_mfma_f32_16x16x32_bf16(af[i], bf[j], acc[i][j], 0, 0, 0);
    }
    __syncthreads();
  }
}

// ---------------- FUSED Q-GEMM + attention ----------------
// Per-wave P/qt region: 64 rows x PSTR(104) shorts = 13312 B; 4 waves = 52 KB (union with
// 32 KB staging) -> 3 blocks/CU. PSTR=104 kills the 8-way PV-read bank conflict of stride 96.
__global__ __launch_bounds__(256, 3) void qattn_kernel(const USHORT* __restrict__ Aw, const USHORT* __restrict__ Bx,
                                                       const float* __restrict__ bias,
                                                       const USHORT* __restrict__ kb, const USHORT* __restrict__ vb,
                                                       USHORT* __restrict__ attnT){
  __shared__ USHORT smem[26624];   // 52 KB
  const int lane = threadIdx.x & 63, wave = threadIdx.x >> 6;
  const int l15 = lane & 15, lg = lane >> 4;
  const int b = blockIdx.z;
  const int xx = xcd_swz32(blockIdx.x);
  const int m0b = blockIdx.y * 128;
  const size_t brow0 = ((size_t)b * NHW + xx * 128) * NC;
  f32x4 acc[4][4];
  gemm128_core(Aw, Bx, m0b, brow0, smem, smem + 8192, acc);

  const int wm = wave >> 1, wn = wave & 1;
  const int h = blockIdx.y * 2 + wm;
  const int m0 = h * 64;                      // head channel base
  const int s0 = xx * 128 + wn * 64;          // this wave's 64 query rows
  const size_t bh = (size_t)b * NHEAD + h;
  char* qt = (char*)(smem + wave * 6656);     // 13 KB wave-private region

  // transpose Q (+bias) into qt[s][d] bf16, XOR-swizzled (row stride 128B)
  #pragma unroll
  for (int i = 0; i < 4; i++){
    const int dbase = i * 16 + lg * 4;
    float b0 = bias[m0 + dbase], b1 = bias[m0 + dbase + 1];
    float b2 = bias[m0 + dbase + 2], b3 = bias[m0 + dbase + 3];
    #pragma unroll
    for (int j = 0; j < 4; j++){
      const int s = j * 16 + l15;
      uint2 pk;
      pk.x = pack2(acc[i][j][0] + b0, acc[i][j][1] + b1);
      pk.y = pack2(acc[i][j][2] + b2, acc[i][j][3] + b3);
      *(uint2*)(qt + s * 128 + ((dbase * 2) ^ ((s & 7) << 4))) = pk;
    }
  }
  // read Q A-fragments (row = s = i*16+l15, k = d contiguous)
  short8 aq[4][2];
  #pragma unroll
  for (int i = 0; i < 4; i++){
    const int s = i * 16 + l15;
    #pragma unroll
    for (int ks = 0; ks < 2; ks++)
      aq[i][ks] = *(const short8*)(qt + s * 128 + ((ks * 64 + lg * 16) ^ ((s & 7) << 4)));
  }

  // P tile reuses the same region: [64][PSTR] bf16. Zero pad cols 80..95 (row = lane).
  USHORT* plds = (USHORT*)qt;
  uint4 z{0u, 0u, 0u, 0u};
  *(uint4*)(qt + lane * (PSTR * 2) + 160) = z;
  *(uint4*)(qt + lane * (PSTR * 2) + 176) = z;

  // K B-fragments (col = token = l15, k = d contiguous)
  short8 bk[5][2];
  const USHORT* kp = kb + bh * TPAD * NDH;
  #pragma unroll
  for (int j = 0; j < 5; j++)
    #pragma unroll
    for (int ks = 0; ks < 2; ks++)
      bk[j][ks] = *(const short8*)(kp + (j * 16 + l15) * NDH + ks * 32 + lg * 8);

  f32x4 sacc[4][5];
  #pragma unroll
  for (int i = 0; i < 4; i++)
    #pragma unroll
    for (int j = 0; j < 5; j++) sacc[i][j] = f32x4{0.f, 0.f, 0.f, 0.f};
  #pragma unroll
  for (int ks = 0; ks < 2; ks++)
    #pragma unroll
    for (int i = 0; i < 4; i++)
      #pragma unroll
      for (int j = 0; j < 5; j++)
        sacc[i][j] = __builtin_amdgcn_mfma_f32_16x16x32_bf16(aq[i][ks], bk[j][ks], sacc[i][j], 0, 0, 0);

  // softmax per row-tile i; rows = lg*4+r live across the 16 lanes sharing lg
  const float scale = 0.125f;
  #pragma unroll
  for (int i = 0; i < 4; i++){
    float v[5][4], mx[4], sm[4];
    #pragma unroll
    for (int r = 0; r < 4; r++) mx[r] = -3.0e38f;
    #pragma unroll
    for (int j = 0; j < 5; j++)
      #pragma unroll
      for (int r = 0; r < 4; r++){
        float t = sacc[i][j][r] * scale;
        if (j == 4 && l15 >= 13) t = -3.0e38f;   // tokens 77..79 masked
        v[j][r] = t;
        mx[r] = fmaxf(mx[r], t);
      }
    #pragma unroll
    for (int r = 0; r < 4; r++)
      #pragma unroll
      for (int d = 1; d < 16; d <<= 1) mx[r] = fmaxf(mx[r], __shfl_xor(mx[r], d));
    #pragma unroll
    for (int r = 0; r < 4; r++) sm[r] = 0.f;
    #pragma unroll
    for (int j = 0; j < 5; j++)
      #pragma unroll
      for (int r = 0; r < 4; r++){
        float p = __expf(v[j][r] - mx[r]);
        v[j][r] = p;
        sm[r] += p;
      }
    #pragma unroll
    for (int r = 0; r < 4; r++)
      #pragma unroll
      for (int d = 1; d < 16; d <<= 1) sm[r] += __shfl_xor(sm[r], d);
    #pragma unroll
    for (int r = 0; r < 4; r++){
      float inv = 1.0f / sm[r];
      #pragma unroll
      for (int j = 0; j < 5; j++)
        plds[(i * 16 + lg * 4 + r) * PSTR + j * 16 + l15] = f2bf(v[j][r] * inv);
    }
  }

  // PV: O^T = V^T (A, from global vb[d][96]) x P^T (B, from LDS plds[s][PSTR])
  f32x4 oacc[4][4];
  #pragma unroll
  for (int it = 0; it < 4; it++)
    #pragma unroll
    for (int jt = 0; jt < 4; jt++) oacc[it][jt] = f32x4{0.f, 0.f, 0.f, 0.f};
  const USHORT* vp = vb + bh * NDH * TPAD2;
  #pragma unroll
  for (int ks = 0; ks < 3; ks++){
    short8 av[4], bpv[4];
    #pragma unroll
    for (int it = 0; it < 4; it++)
      av[it] = *(const short8*)(vp + (it * 16 + l15) * TPAD2 + ks * 32 + lg * 8);
    #pragma unroll
    for (int jt = 0; jt < 4; jt++)
      bpv[jt] = *(const short8*)(plds + (jt * 16 + l15) * PSTR + ks * 32 + lg * 8);
    #pragma unroll
    for (int it = 0; it < 4; it++)
      #pragma unroll
      for (int jt = 0; jt < 4; jt++)
        oacc[it][jt] = __builtin_amdgcn_mfma_f32_16x16x32_bf16(av[it], bpv[jt], oacc[it][jt], 0, 0, 0);
  }

  // epilogue: D row = channel (it*16+lg*4+reg), col = s-local (jt*16+l15); pack 4 channels -> 8B
  USHORT* ob = attnT + ((size_t)b * NHW + s0) * NC + h * NDH;
  #pragma unroll
  for (int it = 0; it < 4; it++)
    #pragma unroll
    for (int jt = 0; jt < 4; jt++){
      const int sl = jt * 16 + l15;
      uint2 pk;
      pk.x = pack2(oacc[it][jt][0], oacc[it][jt][1]);
      pk.y = pack2(oacc[it][jt][2], oacc[it][jt][3]);
      *(uint2*)(ob + (size_t)sl * NC + it * 16 + lg * 4) = pk;
    }
}

// ---------------- proj GEMM + bias + residual -> out fp32 [b][c][hw] ----------------
__global__ __launch_bounds__(256, 3) void projgemm_kernel(const USHORT* __restrict__ Aw, const USHORT* __restrict__ Battn,
                                                          const float* __restrict__ bias, const float* __restrict__ xres,
                                                          float* __restrict__ out){
  __shared__ USHORT Alds[128 * BKS], Blds[128 * BKS];
  const int b = blockIdx.z;
  const int xx = xcd_swz32(blockIdx.x);
  const int m0b = blockIdx.y * 128;
  const size_t brow0 = ((size_t)b * NHW + xx * 128) * NC;
  f32x4 acc[4][4];
  gemm128_core(Aw, Battn, m0b, brow0, Alds, Blds, acc);

  const int lane = threadIdx.x & 63, wave = threadIdx.x >> 6;
  const int l15 = lane & 15, lg = lane >> 4;
  const int m0 = m0b + (wave >> 1) * 64;
  const int n0 = xx * 128 + (wave & 1) * 64;
  #pragma unroll
  for (int i = 0; i < 4; i++){
    const int ob = m0 + i * 16 + lg * 4;
    #pragma unroll
    for (int r = 0; r < 4; r++){
      const int oc = ob + r;
      const float bb = bias[oc];
      #pragma unroll
      for (int j = 0; j < 4; j++){
        const int s = n0 + j * 16 + l15;
        const size_t idx = ((size_t)b * NC + oc) * NHW + s;
        out[idx] = acc[i][j][r] + bb + xres[idx];
      }
    }
  }
}

// ---------------- small-K MFMA core for the 77-token projections ----------------
template<int KLEN>
__device__ __forceinline__ void mfma_core(const USHORT* const (&ap)[4], const USHORT* const (&bp)[4],
                                          f32x4 (&acc)[4][4]){
  short8 a_c[4], b_c[4];
  #pragma unroll
  for (int i = 0; i < 4; i++){ a_c[i] = *(const short8*)ap[i]; b_c[i] = *(const short8*)bp[i]; }
  #pragma unroll 2
  for (int k0 = 0; k0 < KLEN; k0 += 32){
    short8 a_n[4], b_n[4];
    if (k0 + 32 < KLEN){
      #pragma unroll
      for (int i = 0; i < 4; i++){
        a_n[i] = *(const short8*)(ap[i] + k0 + 32);
        b_n[i] = *(const short8*)(bp[i] + k0 + 32);
      }
    }
    #pragma unroll
    for (int i = 0; i < 4; i++)
      #pragma unroll
      for (int j = 0; j < 4; j++)
        acc[i][j] = __builtin_amdgcn_mfma_f32_16x16x32_bf16(a_c[i], b_c[j], acc[i][j], 0, 0, 0);
    #pragma unroll
    for (int i = 0; i < 4; i++){ a_c[i] = a_n[i]; b_c[i] = b_n[i]; }
  }
}

// ---------------- K+V GEMM (single launch, mode = blockIdx.y) + raw-reshape scatter ----------------
__global__ __launch_bounds__(256, 2) void kvgemm_kernel(const USHORT* __restrict__ kw, const USHORT* __restrict__ vw,
                                                        const USHORT* __restrict__ Tx,
                                                        const float* __restrict__ kbias, const float* __restrict__ vbias,
                                                        USHORT* __restrict__ kdst, USHORT* __restrict__ vdst){
  const int lane = threadIdx.x & 63, wave = threadIdx.x >> 6;
  const int l15 = lane & 15, lg = lane >> 4;
  const int b = blockIdx.z;
  const int mode = blockIdx.y;
  const USHORT* Wt = mode ? vw : kw;
  const float* bias = mode ? vbias : kbias;
  USHORT* dst = mode ? vdst : kdst;
  const int m0 = (wave >> 1) * 64;                    // token tile base
  const int n0 = blockIdx.x * 128 + (wave & 1) * 64;  // channel base
  const USHORT* ap[4]; const USHORT* bp[4];
  #pragma unroll
  for (int i = 0; i < 4; i++){
    int r = m0 + i * 16 + l15; r = r > 76 ? 76 : r;
    ap[i] = Tx + ((size_t)b * NT + r) * NF + lg * 8;
  }
  #pragma unroll
  for (int i = 0; i < 4; i++) bp[i] = Wt + (size_t)(n0 + i * 16 + l15) * NF + lg * 8;
  f32x4 acc[4][4];
  #pragma unroll
  for (int i = 0; i < 4; i++)
    #pragma unroll
    for (int j = 0; j < 4; j++) acc[i][j] = f32x4{0.f, 0.f, 0.f, 0.f};
  mfma_core<NF>(ap, bp, acc);
  #pragma unroll
  for (int i = 0; i < 4; i++){
    const int tb = m0 + i * 16 + lg * 4;
    #pragma unroll
    for (int r = 0; r < 4; r++){
      const int t = tb + r;
      if (t < NT){
        #pragma unroll
        for (int j = 0; j < 4; j++){
          const int c = n0 + j * 16 + l15;
          float v = acc[i][j][r] + bias[c];
          // raw reshape (b,77,512)->(b,8,64,77): flat i = t*512+c -> h=i/4928, d=(i%4928)/77, tt=i%77
          int fi = t * NC + c;
          int hh = fi / 4928;
          int rem = fi - hh * 4928;
          int dd = rem / 77;
          int tt = rem - dd * 77;
          size_t bhh = (size_t)(b * NHEAD + hh);
          if (mode == 0) dst[(bhh * TPAD + tt) * NDH + dd] = f2bf(v);
          else           dst[(bhh * NDH + dd) * TPAD2 + tt] = f2bf(v);
        }
      }
    }
  }
}

extern "C" void kernel_launch(void* const* d_in, const int* in_sizes, int n_in,
                              void* d_out, int out_size, void* d_ws, size_t ws_size,
                              hipStream_t stream){
  const float* x    = (const float*)d_in[0];
  const float* text = (const float*)d_in[1];
  const float* gn_g = (const float*)d_in[2];
  const float* gn_b = (const float*)d_in[3];
  const float* q_w  = (const float*)d_in[4];
  const float* q_b  = (const float*)d_in[5];
  const float* k_w  = (const float*)d_in[6];
  const float* k_b  = (const float*)d_in[7];
  const float* v_w  = (const float*)d_in[8];
  const float* v_b  = (const float*)d_in[9];
  const float* p_w  = (const float*)d_in[10];
  const float* p_b  = (const float*)d_in[11];
  float* out = (float*)d_out;

  char* ws = (char*)d_ws;
  size_t off = 0;
  auto alloc = [&](size_t bytes){ size_t o = off; off = (off + bytes + 255) & ~(size_t)255; return o; };
  size_t o_stats = alloc(512 * 8);
  size_t o_qwb   = alloc((size_t)NC * NC * 2);
  size_t o_pwb   = alloc((size_t)NC * NC * 2);
  size_t o_kwb   = alloc((size_t)NC * NF * 2);
  size_t o_vwb   = alloc((size_t)NC * NF * 2);
  size_t o_txb   = alloc((size_t)NB * NT * NF * 2);
  size_t o_kb    = alloc((size_t)NB * NHEAD * TPAD * NDH * 2);
  size_t o_vb    = alloc((size_t)NB * NHEAD * NDH * TPAD2 * 2);
  size_t o_xnT   = alloc((size_t)NB * NHW * NC * 2);
  size_t o_attnT = alloc((size_t)NB * NHW * NC * 2);
  (void)ws_size; (void)in_sizes; (void)n_in; (void)out_size;

  float2* stats = (float2*)(ws + o_stats);
  USHORT* qwb = (USHORT*)(ws + o_qwb);
  USHORT* pwb = (USHORT*)(ws + o_pwb);
  USHORT* kwb = (USHORT*)(ws + o_kwb);
  USHORT* vwb = (USHORT*)(ws + o_vwb);
  USHORT* txb = (USHORT*)(ws + o_txb);
  USHORT* kbuf = (USHORT*)(ws + o_kb);
  USHORT* vbuf = (USHORT*)(ws + o_vb);
  USHORT* xnT = (USHORT*)(ws + o_xnT);
  USHORT* attnT = (USHORT*)(ws + o_attnT);

  // single convert launch: q_w, p_w, k_w, v_w, text (sizes in float4 units)
  const int n0 = (NC * NC) / 4, n1 = (NC * NC) / 4, n2 = (NC * NF) / 4, n3 = (NC * NF) / 4,
            n4 = (NB * NT * NF) / 4;
  const int ntot = n0 + n1 + n2 + n3 + n4;
  hipLaunchKernelGGL(cvt_all_kernel, dim3((ntot + 255) / 256), dim3(256), 0, stream,
                     q_w, qwb, n0, p_w, pwb, n1, k_w, kwb, n2, v_w, vwb, n3, text, txb, n4);

  hipLaunchKernelGGL(gnstats_kernel, dim3(512), dim3(256), 0, stream, x, stats);
  hipLaunchKernelGGL(gnorm_tr_kernel, dim3(64, 8, 16), dim3(256), 0, stream, x, stats, gn_g, gn_b, xnT);
  hipLaunchKernelGGL(kvgemm_kernel, dim3(4, 2, 16), dim3(256), 0, stream, kwb, vwb, txb, k_b, v_b, kbuf, vbuf);
  hipLaunchKernelGGL(qattn_kernel, dim3(32, 4, 16), dim3(256), 0, stream, qwb, xnT, q_b, kbuf, vbuf, attnT);
  hipLaunchKernelGGL(projgemm_kernel, dim3(32, 4, 16), dim3(256), 0, stream, pwb, attnT, p_b, x, out);
}